// Round 4
// baseline (2616.364 us; speedup 1.0000x reference)
//
#include <hip/hip_runtime.h>
#include <hip/hip_bf16.h>

typedef __hip_bfloat16 bf16;

__device__ __forceinline__ float tof(float x) { return x; }
__device__ __forceinline__ float tof(bf16 x) { return __bfloat162float(x); }
__device__ __forceinline__ bf16 tobf(float x) { return __float2bfloat16(x); }

__device__ __forceinline__ void storec(float* p, long i, float v) { p[i] = v; }
__device__ __forceinline__ void storec(bf16* p, long i, float v) { p[i] = tobf(v); }

// monotone f32 -> u32 map for atomicMax on floats
__device__ __forceinline__ unsigned f2mono(float f) {
    unsigned u = __float_as_uint(f);
    return (u & 0x80000000u) ? ~u : (u | 0x80000000u);
}
__device__ __forceinline__ float mono2f(unsigned u) {
    unsigned b = (u & 0x80000000u) ? (u & 0x7fffffffu) : ~u;
    return __uint_as_float(b);
}

// ---- tiled GEMM: C[M,N] = A[M,K] @ B[K,:] (row stride ldb), f32 accum -----
// 64x64 tile, 256 threads, 4x4 microtile. K%16==0, N%64==0 required.
template <typename TA, typename TB, typename TC>
__global__ __launch_bounds__(256) void gemm_tiled(
    const TA* __restrict__ A, const TB* __restrict__ B, TC* __restrict__ C,
    int M, int N, int K, int ldb)
{
    __shared__ float As[16][68];
    __shared__ float Bs[16][68];
    const int tid = threadIdx.x;
    const long bm = (long)blockIdx.y * 64;
    const int bn = blockIdx.x * 64;
    const int ty = tid >> 4;
    const int tx = tid & 15;
    const int ar_loc = tid >> 2;
    const long ar = bm + ar_loc;
    const int ak = (tid & 3) * 4;
    const int bk = tid >> 4;
    const int bc = (tid & 15) * 4;
    float acc[4][4] = {{0.f,0.f,0.f,0.f},{0.f,0.f,0.f,0.f},
                       {0.f,0.f,0.f,0.f},{0.f,0.f,0.f,0.f}};
    for (int k0 = 0; k0 < K; k0 += 16) {
        if (ar < M) {
#pragma unroll
            for (int i = 0; i < 4; ++i)
                As[ak + i][ar_loc] = tof(A[ar * K + k0 + ak + i]);
        } else {
#pragma unroll
            for (int i = 0; i < 4; ++i) As[ak + i][ar_loc] = 0.f;
        }
#pragma unroll
        for (int i = 0; i < 4; ++i)
            Bs[bk][bc + i] = tof(B[(long)(k0 + bk) * ldb + bn + bc + i]);
        __syncthreads();
#pragma unroll
        for (int k = 0; k < 16; ++k) {
            float4 av = *(const float4*)&As[k][ty * 4];
            float4 bv = *(const float4*)&Bs[k][tx * 4];
            float a_[4] = {av.x, av.y, av.z, av.w};
            float b_[4] = {bv.x, bv.y, bv.z, bv.w};
#pragma unroll
            for (int i = 0; i < 4; ++i)
#pragma unroll
                for (int j = 0; j < 4; ++j) acc[i][j] += a_[i] * b_[j];
        }
        __syncthreads();
    }
#pragma unroll
    for (int i = 0; i < 4; ++i) {
        long r = bm + ty * 4 + i;
        if (r < M) {
#pragma unroll
            for (int j = 0; j < 4; ++j)
                storec(C, r * N + bn + tx * 4 + j, acc[i][j]);
        }
    }
}

// ---- layer-1 attention logits, 4 heads: [N,4] --------------------------
__global__ void alpha4_k(const bf16* __restrict__ h, const float* __restrict__ asrc,
                         const float* __restrict__ adst, float* __restrict__ out_s,
                         float* __restrict__ out_d, int N)
{
    int i = blockIdx.x * blockDim.x + threadIdx.x;
    if (i >= N * 4) return;
    int n = i >> 2, hh = i & 3;
    const bf16* row = h + (long)n * 128 + hh * 32;
    const float* av = asrc + hh * 32;
    const float* bv = adst + hh * 32;
    float s1 = 0.f, s2 = 0.f;
    for (int c = 0; c < 32; ++c) {
        float v = tof(row[c]);
        s1 += v * av[c];
        s2 += v * bv[c];
    }
    out_s[i] = s1;
    out_d[i] = s2;
}

// ---- layer-2 attention logits, single head: [N] ------------------------
__global__ void alpha1_k(const bf16* __restrict__ h2c, const float* __restrict__ as_,
                         const float* __restrict__ ad_, float* __restrict__ out_s,
                         float* __restrict__ out_d, int N)
{
    int n = blockIdx.x * blockDim.x + threadIdx.x;
    if (n >= N) return;
    const bf16* row = h2c + (long)n * 128;
    float s1 = 0.f, s2 = 0.f;
    for (int c = 0; c < 128; ++c) {
        float v = tof(row[c]);
        s1 += v * as_[c];
        s2 += v * ad_[c];
    }
    out_s[n] = s1;
    out_d[n] = s2;
}

// ---- zero softmax state (+ optional f32 accumulator) -------------------
__global__ void zero_k(unsigned* __restrict__ mx, float* __restrict__ dn,
                       float* __restrict__ acc, int nmd, long nacc)
{
    long i = (long)blockIdx.x * blockDim.x + threadIdx.x;
    if (i < nmd) { mx[i] = 0u; dn[i] = 0.f; }
    if (acc && i < nacc) acc[i] = 0.f;
}

__global__ void init_emb_k(float* __restrict__ emb, const float* __restrict__ b2, long n)
{
    long i = (long)blockIdx.x * blockDim.x + threadIdx.x;
    if (i >= n) return;
    emb[i] = b2[i & 127];
}

// ---- edge softmax, 4-head variants (layer 1) ---------------------------
__global__ void edge_max4_k(const int* __restrict__ src, const int* __restrict__ dst,
                            int E, int Etot, const float* __restrict__ as_,
                            const float* __restrict__ ad_, unsigned* __restrict__ mx)
{
    int g = blockIdx.x * blockDim.x + threadIdx.x;
    if (g >= Etot * 4) return;
    int e = g >> 2, hh = g & 3;
    int s, d;
    if (e < E) { s = src[e]; d = dst[e]; } else { s = d = e - E; }
    float v = as_[s * 4 + hh] + ad_[d * 4 + hh];
    v = v > 0.f ? v : 0.2f * v;
    atomicMax(&mx[d * 4 + hh], f2mono(v));
}

__global__ void edge_exp4_k(const int* __restrict__ src, const int* __restrict__ dst,
                            int E, int Etot, const float* __restrict__ as_,
                            const float* __restrict__ ad_, const unsigned* __restrict__ mx,
                            float* __restrict__ dn, float* __restrict__ alp)
{
    int g = blockIdx.x * blockDim.x + threadIdx.x;
    if (g >= Etot * 4) return;
    int e = g >> 2, hh = g & 3;
    int s, d;
    if (e < E) { s = src[e]; d = dst[e]; } else { s = d = e - E; }
    float v = as_[s * 4 + hh] + ad_[d * 4 + hh];
    v = v > 0.f ? v : 0.2f * v;
    float w = expf(v - mono2f(mx[d * 4 + hh]));
    alp[g] = w;
    atomicAdd(&dn[d * 4 + hh], w);
}

// ---- edge softmax, single-head variants (layer 2) ----------------------
__global__ void edge_max1_k(const int* __restrict__ src, const int* __restrict__ dst,
                            int E, int Etot, const float* __restrict__ as_,
                            const float* __restrict__ ad_, unsigned* __restrict__ mx)
{
    int e = blockIdx.x * blockDim.x + threadIdx.x;
    if (e >= Etot) return;
    int s, d;
    if (e < E) { s = src[e]; d = dst[e]; } else { s = d = e - E; }
    float v = as_[s] + ad_[d];
    v = v > 0.f ? v : 0.2f * v;
    atomicMax(&mx[d], f2mono(v));
}

__global__ void edge_exp1_k(const int* __restrict__ src, const int* __restrict__ dst,
                            int E, int Etot, const float* __restrict__ as_,
                            const float* __restrict__ ad_, const unsigned* __restrict__ mx,
                            float* __restrict__ dn, float* __restrict__ alp)
{
    int e = blockIdx.x * blockDim.x + threadIdx.x;
    if (e >= Etot) return;
    int s, d;
    if (e < E) { s = src[e]; d = dst[e]; } else { s = d = e - E; }
    float v = as_[s] + ad_[d];
    v = v > 0.f ? v : 0.2f * v;
    float w = expf(v - mono2f(mx[d]));
    alp[e] = w;
    atomicAdd(&dn[d], w);
}

// ---- layer-1 aggregation (4 heads, h1 bf16, f32 atomics) ---------------
__global__ void agg1_k(const int* __restrict__ src, const int* __restrict__ dst,
                       int E, int Etot, const float* __restrict__ alp,
                       const float* __restrict__ dn, const bf16* __restrict__ h1,
                       float* __restrict__ out)
{
    long g = (long)blockIdx.x * blockDim.x + threadIdx.x;
    if (g >= (long)Etot * 128) return;
    int e = (int)(g >> 7);
    int t = (int)(g & 127);
    int s, d;
    if (e < E) { s = src[e]; d = dst[e]; } else { s = d = e - E; }
    int hh = t >> 5;
    float coef = alp[e * 4 + hh] / (dn[d * 4 + hh] + 1e-16f);
    atomicAdd(&out[(long)d * 128 + t], coef * tof(h1[(long)s * 128 + t]));
}

// ---- layer-2 aggregation, one head (h2c bf16, 0.25x into emb f32) ------
__global__ void agg2h_k(const int* __restrict__ src, const int* __restrict__ dst,
                        int E, int Etot, const float* __restrict__ alp,
                        const float* __restrict__ dn, const bf16* __restrict__ h2c,
                        float* __restrict__ emb)
{
    long g = (long)blockIdx.x * blockDim.x + threadIdx.x;
    if (g >= (long)Etot * 128) return;
    int e = (int)(g >> 7);
    int c = (int)(g & 127);
    int s, d;
    if (e < E) { s = src[e]; d = dst[e]; } else { s = d = e - E; }
    float coef = 0.25f * alp[e] / (dn[d] + 1e-16f);
    atomicAdd(&emb[(long)d * 128 + c], coef * tof(h2c[(long)s * 128 + c]));
}

// ---- bias + ELU, f32 -> bf16 -------------------------------------------
__global__ void bias_elu_bf_k(const float* __restrict__ xf, const float* __restrict__ b,
                              bf16* __restrict__ ob, long n)
{
    long i = (long)blockIdx.x * blockDim.x + threadIdx.x;
    if (i >= n) return;
    float v = xf[i] + b[i & 127];
    v = v > 0.f ? v : (expf(v) - 1.f);
    ob[i] = tobf(v);
}

// ---- final linear: out[N,64] = emb[N,128] @ W_lin + b ------------------
__global__ __launch_bounds__(256) void final_k(const float* __restrict__ emb,
                                               const float* __restrict__ W,
                                               const float* __restrict__ bias,
                                               float* __restrict__ out, int N)
{
    __shared__ float Ws[128 * 64];
    __shared__ float Es[4][132];
    const int tid = threadIdx.x;
    for (int i = tid; i < 128 * 64; i += 256) Ws[i] = W[i];
    int node0 = blockIdx.x * 4;
    for (int i = tid; i < 512; i += 256) {
        int nn = i >> 7, c = i & 127;
        int n = node0 + nn;
        Es[nn][c] = (n < N) ? emb[(long)n * 128 + c] : 0.f;
    }
    __syncthreads();
    int nn = tid >> 6, j = tid & 63;
    int n = node0 + nn;
    if (n >= N) return;
    float acc = bias[j];
#pragma unroll 8
    for (int k = 0; k < 128; ++k) acc += Es[nn][k] * Ws[k * 64 + j];
    out[(long)n * 64 + j] = acc;
}

__global__ void copy_k(const float* __restrict__ srcp, float* __restrict__ dstp, long n)
{
    long i = (long)blockIdx.x * blockDim.x + threadIdx.x;
    if (i >= n) return;
    dstp[i] = srcp[i];
}

// ---- diagnostic: fill output with a constant encoding ws_size ----------
__global__ void diag_k(float* __restrict__ out, long n, float val)
{
    long i = (long)blockIdx.x * blockDim.x + threadIdx.x;
    if (i >= n) return;
    out[i] = val;
}

extern "C" void kernel_launch(void* const* d_in, const int* in_sizes, int n_in,
                              void* d_out, int out_size, void* d_ws, size_t ws_size,
                              hipStream_t stream)
{
    const float* x   = (const float*)d_in[0];
    const int* ei    = (const int*)d_in[1];
    const float* W1  = (const float*)d_in[2];
    const float* as1 = (const float*)d_in[3];
    const float* ad1 = (const float*)d_in[4];
    const float* b1  = (const float*)d_in[5];
    const float* W2  = (const float*)d_in[6];
    const float* as2 = (const float*)d_in[7];
    const float* ad2 = (const float*)d_in[8];
    const float* b2  = (const float*)d_in[9];
    const float* Wl  = (const float*)d_in[10];
    const float* bl  = (const float*)d_in[11];

    const int N = in_sizes[0] / 512;
    const int E = in_sizes[1] / 2;
    const int Etot = E + N;
    const int* src = ei;
    const int* dst = ei + E;

    float* outp = (float*)d_out;          // [N,64]
    float* embp = outp + (size_t)N * 64;  // [N,128]

    // ---- workspace layout, 120.0 MB total (known safe from R3 diag) ----
    // R1 [0, 25.6M):     h1 bf16 [N,128]  -> later out1b bf16 [N,128]
    // R2 [25.6M,76.8M):  out1f f32 [N,128] -> later emb f32 [N,128]
    // R4 [76.8M,102.4M): h2c bf16 [N,128] (per-head chunk)
    // S  [102.4M,120M):  asv/adv/mx/dn [N*4] f32 each + alp [Etot*4] f32
    char* wsb = (char*)d_ws;
    size_t nb_R1 = (size_t)N * 128 * sizeof(bf16);
    size_t nb_R2 = (size_t)N * 128 * sizeof(float);
    size_t nb_R4 = (size_t)N * 128 * sizeof(bf16);
    bf16*  h1    = (bf16*)wsb;
    bf16*  out1b = (bf16*)wsb;                       // reuse R1 after agg1
    float* out1f = (float*)(wsb + nb_R1);
    float* emb   = out1f;                            // reuse R2 after bias_elu
    bf16*  h2c   = (bf16*)(wsb + nb_R1 + nb_R2);
    float* asv   = (float*)(wsb + nb_R1 + nb_R2 + nb_R4);
    float* adv   = asv + (size_t)N * 4;
    unsigned* mx = (unsigned*)(adv + (size_t)N * 4);
    float* dn    = (float*)(mx + (size_t)N * 4);
    float* alp   = dn + (size_t)N * 4;
    size_t need  = (size_t)((char*)(alp + (size_t)Etot * 4) - wsb);

    dim3 blk(256);
    long n_out_total = (long)N * 192;

    if (ws_size < need) {
        float val = 100.0f + (float)(ws_size >> 20);
        diag_k<<<(int)((n_out_total + 255) / 256), blk, 0, stream>>>(outp, n_out_total, val);
        return;
    }

    const int na = N * 4;
    const int ne4 = Etot * 4;
    const long nagg = (long)Etot * 128;
    const long nrow = (long)N * 128;
    const int gRow = (int)((nrow + 255) / 256);
    const int gAgg = (int)((nagg + 255) / 256);
    const int gMy = (N + 63) / 64;

    // ---- layer 1 ----
    gemm_tiled<float, float, bf16><<<dim3(2, gMy), blk, 0, stream>>>(x, W1, h1, N, 128, 512, 128);
    alpha4_k<<<(na + 255) / 256, blk, 0, stream>>>(h1, as1, ad1, asv, adv, N);
    zero_k<<<gRow, blk, 0, stream>>>(mx, dn, out1f, na, nrow);
    edge_max4_k<<<(ne4 + 255) / 256, blk, 0, stream>>>(src, dst, E, Etot, asv, adv, mx);
    edge_exp4_k<<<(ne4 + 255) / 256, blk, 0, stream>>>(src, dst, E, Etot, asv, adv, mx, dn, alp);
    agg1_k<<<gAgg, blk, 0, stream>>>(src, dst, E, Etot, alp, dn, h1, out1f);
    bias_elu_bf_k<<<gRow, blk, 0, stream>>>(out1f, b1, out1b, nrow);

    // ---- layer 2, per head ----
    init_emb_k<<<gRow, blk, 0, stream>>>(emb, b2, nrow);
    for (int h = 0; h < 4; ++h) {
        gemm_tiled<bf16, float, bf16><<<dim3(2, gMy), blk, 0, stream>>>(
            out1b, W2 + h * 128, h2c, N, 128, 128, 512);
        alpha1_k<<<(N + 255) / 256, blk, 0, stream>>>(h2c, as2 + h * 128, ad2 + h * 128, asv, adv, N);
        zero_k<<<(N + 255) / 256, blk, 0, stream>>>(mx, dn, (float*)nullptr, N, 0);
        edge_max1_k<<<(Etot + 255) / 256, blk, 0, stream>>>(src, dst, E, Etot, asv, adv, mx);
        edge_exp1_k<<<(Etot + 255) / 256, blk, 0, stream>>>(src, dst, E, Etot, asv, adv, mx, dn, alp);
        agg2h_k<<<gAgg, blk, 0, stream>>>(src, dst, E, Etot, alp, dn, h2c, emb);
    }

    // ---- head ----
    final_k<<<(N + 3) / 4, blk, 0, stream>>>(emb, Wl, bl, outp, N);
    copy_k<<<gRow, blk, 0, stream>>>(emb, embp, nrow);
}

// Round 5
// 1293.914 us; speedup vs baseline: 2.0221x; 2.0221x over previous
//
#include <hip/hip_runtime.h>
#include <hip/hip_bf16.h>

typedef __hip_bfloat16 bf16;

__device__ __forceinline__ float tof(float x) { return x; }
__device__ __forceinline__ float tof(bf16 x) { return __bfloat162float(x); }
__device__ __forceinline__ bf16 tobf(float x) { return __float2bfloat16(x); }

__device__ __forceinline__ void storec(float* p, long i, float v) { p[i] = v; }
__device__ __forceinline__ void storec(bf16* p, long i, float v) { p[i] = tobf(v); }

// ---- tiled GEMM: C[M,N] = A[M,K] @ B[K,:] (row stride ldb), f32 accum -----
template <typename TA, typename TB, typename TC>
__global__ __launch_bounds__(256) void gemm_tiled(
    const TA* __restrict__ A, const TB* __restrict__ B, TC* __restrict__ C,
    int M, int N, int K, int ldb)
{
    __shared__ float As[16][68];
    __shared__ float Bs[16][68];
    const int tid = threadIdx.x;
    const long bm = (long)blockIdx.y * 64;
    const int bn = blockIdx.x * 64;
    const int ty = tid >> 4;
    const int tx = tid & 15;
    const int ar_loc = tid >> 2;
    const long ar = bm + ar_loc;
    const int ak = (tid & 3) * 4;
    const int bk = tid >> 4;
    const int bc = (tid & 15) * 4;
    float acc[4][4] = {{0.f,0.f,0.f,0.f},{0.f,0.f,0.f,0.f},
                       {0.f,0.f,0.f,0.f},{0.f,0.f,0.f,0.f}};
    for (int k0 = 0; k0 < K; k0 += 16) {
        if (ar < M) {
#pragma unroll
            for (int i = 0; i < 4; ++i)
                As[ak + i][ar_loc] = tof(A[ar * K + k0 + ak + i]);
        } else {
#pragma unroll
            for (int i = 0; i < 4; ++i) As[ak + i][ar_loc] = 0.f;
        }
#pragma unroll
        for (int i = 0; i < 4; ++i)
            Bs[bk][bc + i] = tof(B[(long)(k0 + bk) * ldb + bn + bc + i]);
        __syncthreads();
#pragma unroll
        for (int k = 0; k < 16; ++k) {
            float4 av = *(const float4*)&As[k][ty * 4];
            float4 bv = *(const float4*)&Bs[k][tx * 4];
            float a_[4] = {av.x, av.y, av.z, av.w};
            float b_[4] = {bv.x, bv.y, bv.z, bv.w};
#pragma unroll
            for (int i = 0; i < 4; ++i)
#pragma unroll
                for (int j = 0; j < 4; ++j) acc[i][j] += a_[i] * b_[j];
        }
        __syncthreads();
    }
#pragma unroll
    for (int i = 0; i < 4; ++i) {
        long r = bm + ty * 4 + i;
        if (r < M) {
#pragma unroll
            for (int j = 0; j < 4; ++j)
                storec(C, r * N + bn + tx * 4 + j, acc[i][j]);
        }
    }
}

// ---- layer-1 attention logits, 4 heads of C=32: [N,4] -------------------
__global__ void alpha4_k(const bf16* __restrict__ h, const float* __restrict__ asrc,
                         const float* __restrict__ adst, float* __restrict__ out_s,
                         float* __restrict__ out_d, int N)
{
    int i = blockIdx.x * blockDim.x + threadIdx.x;
    if (i >= N * 4) return;
    int n = i >> 2, hh = i & 3;
    const bf16* row = h + (long)n * 128 + hh * 32;
    const float* av = asrc + hh * 32;
    const float* bv = adst + hh * 32;
    float s1 = 0.f, s2 = 0.f;
    for (int c = 0; c < 32; ++c) {
        float v = tof(row[c]);
        s1 += v * av[c];
        s2 += v * bv[c];
    }
    out_s[i] = s1;
    out_d[i] = s2;
}

// ---- layer-2 attention logits: one wave per (node, head), C=128 ---------
__global__ __launch_bounds__(256) void alpha2w_k(
    const bf16* __restrict__ h2, const float* __restrict__ as2,
    const float* __restrict__ ad2, float* __restrict__ out_s,
    float* __restrict__ out_d, int N)
{
    int n = blockIdx.x;
    int w = threadIdx.x >> 6;   // head
    int l = threadIdx.x & 63;
    const bf16* row = h2 + (long)n * 512 + w * 128;
    float v0 = tof(row[l]), v1 = tof(row[l + 64]);
    float s1 = v0 * as2[w * 128 + l] + v1 * as2[w * 128 + l + 64];
    float s2 = v0 * ad2[w * 128 + l] + v1 * ad2[w * 128 + l + 64];
#pragma unroll
    for (int off = 32; off; off >>= 1) {
        s1 += __shfl_down(s1, off);
        s2 += __shfl_down(s2, off);
    }
    if (l == 0) { out_s[n * 4 + w] = s1; out_d[n * 4 + w] = s2; }
}

// ---- CSR build ----------------------------------------------------------
__global__ void init_cnt_k(int* __restrict__ cnt, int N)
{
    int i = blockIdx.x * blockDim.x + threadIdx.x;
    if (i < N) cnt[i] = 1;  // self-loop
}

__global__ void hist_k(const int* __restrict__ dst, int E, int* __restrict__ cnt)
{
    int e = blockIdx.x * blockDim.x + threadIdx.x;
    if (e < E) atomicAdd(&cnt[dst[e]], 1);
}

__global__ __launch_bounds__(256) void scan_blk_k(const int* __restrict__ cnt,
                                                  int* __restrict__ row_ptr,
                                                  int* __restrict__ bsum, int N)
{
    __shared__ int s[256];
    int t = threadIdx.x;
    int i = blockIdx.x * 256 + t;
    int v = (i < N) ? cnt[i] : 0;
    s[t] = v;
    __syncthreads();
    for (int off = 1; off < 256; off <<= 1) {
        int x = (t >= off) ? s[t - off] : 0;
        __syncthreads();
        s[t] += x;
        __syncthreads();
    }
    if (i < N) row_ptr[i] = s[t] - v;  // exclusive
    if (t == 255) bsum[blockIdx.x] = s[255];
}

__global__ __launch_bounds__(512) void scan_top_k(const int* __restrict__ bsum,
                                                  int* __restrict__ bofs, int B)
{
    __shared__ int s[512];
    int t = threadIdx.x;
    int v = (t < B) ? bsum[t] : 0;
    s[t] = v;
    __syncthreads();
    for (int off = 1; off < 512; off <<= 1) {
        int x = (t >= off) ? s[t - off] : 0;
        __syncthreads();
        s[t] += x;
        __syncthreads();
    }
    bofs[t] = s[t] - v;  // exclusive
}

__global__ void add_off_k(int* __restrict__ row_ptr, const int* __restrict__ bofs,
                          int* __restrict__ wofs, int N, int Etot)
{
    int i = blockIdx.x * blockDim.x + threadIdx.x;
    if (i == 0) row_ptr[N] = Etot;
    if (i >= N) return;
    int r = row_ptr[i] + bofs[i >> 8];
    row_ptr[i] = r;
    wofs[i] = r;
}

__global__ void scatter_k(const int* __restrict__ dst, int E, int Etot,
                          int* __restrict__ wofs, int* __restrict__ eidx)
{
    int e = blockIdx.x * blockDim.x + threadIdx.x;
    if (e >= Etot) return;
    int d = (e < E) ? dst[e] : (e - E);
    int pos = atomicAdd(&wofs[d], 1);
    eidx[pos] = e;
}

// ---- layer-1: fused per-node softmax + gather-aggregate + bias + ELU ----
// block = one dst node, 128 threads = output channels (head = t>>5).
__global__ __launch_bounds__(128) void agg1_gather_k(
    const int* __restrict__ row_ptr, const int* __restrict__ eidx,
    const int* __restrict__ src, int E,
    const float* __restrict__ asv, const float* __restrict__ adv,
    const bf16* __restrict__ h1, const float* __restrict__ b1,
    bf16* __restrict__ out1b)
{
    int d = blockIdx.x;
    int t = threadIdx.x;
    int hh = t >> 5;
    int beg = row_ptr[d], end = row_ptr[d + 1];
    float ad_d = adv[d * 4 + hh];
    float m = -1e30f;
    for (int j = beg; j < end; ++j) {
        int e = eidx[j];
        int s = (e < E) ? src[e] : d;
        float l = asv[s * 4 + hh] + ad_d;
        l = l > 0.f ? l : 0.2f * l;
        m = fmaxf(m, l);
    }
    float den = 0.f, acc = 0.f;
    for (int j = beg; j < end; ++j) {
        int e = eidx[j];
        int s = (e < E) ? src[e] : d;
        float l = asv[s * 4 + hh] + ad_d;
        l = l > 0.f ? l : 0.2f * l;
        float w = __expf(l - m);
        den += w;
        acc += w * tof(h1[(long)s * 128 + t]);
    }
    float v = acc / (den + 1e-16f) + b1[t];
    v = v > 0.f ? v : (__expf(v) - 1.f);
    out1b[(long)d * 128 + t] = tobf(v);
}

// ---- layer-2: fused per-node 4-head softmax + gather + head-mean + bias --
// block = one dst node, 128 threads = channels c; writes emb f32 directly.
__global__ __launch_bounds__(128) void agg2_gather_k(
    const int* __restrict__ row_ptr, const int* __restrict__ eidx,
    const int* __restrict__ src, int E,
    const float* __restrict__ asv, const float* __restrict__ adv,
    const bf16* __restrict__ h2, const float* __restrict__ b2,
    float* __restrict__ emb)
{
    int d = blockIdx.x;
    int c = threadIdx.x;
    int beg = row_ptr[d], end = row_ptr[d + 1];
    float ad0 = adv[d * 4 + 0], ad1 = adv[d * 4 + 1];
    float ad2_ = adv[d * 4 + 2], ad3 = adv[d * 4 + 3];
    float m0 = -1e30f, m1 = -1e30f, m2 = -1e30f, m3 = -1e30f;
    for (int j = beg; j < end; ++j) {
        int e = eidx[j];
        int s = (e < E) ? src[e] : d;
        float l0 = asv[s * 4 + 0] + ad0; l0 = l0 > 0.f ? l0 : 0.2f * l0;
        float l1 = asv[s * 4 + 1] + ad1; l1 = l1 > 0.f ? l1 : 0.2f * l1;
        float l2 = asv[s * 4 + 2] + ad2_; l2 = l2 > 0.f ? l2 : 0.2f * l2;
        float l3 = asv[s * 4 + 3] + ad3; l3 = l3 > 0.f ? l3 : 0.2f * l3;
        m0 = fmaxf(m0, l0); m1 = fmaxf(m1, l1);
        m2 = fmaxf(m2, l2); m3 = fmaxf(m3, l3);
    }
    float d0 = 0.f, d1 = 0.f, d2 = 0.f, d3 = 0.f;
    float a0 = 0.f, a1 = 0.f, a2 = 0.f, a3 = 0.f;
    for (int j = beg; j < end; ++j) {
        int e = eidx[j];
        int s = (e < E) ? src[e] : d;
        float l0 = asv[s * 4 + 0] + ad0; l0 = l0 > 0.f ? l0 : 0.2f * l0;
        float l1 = asv[s * 4 + 1] + ad1; l1 = l1 > 0.f ? l1 : 0.2f * l1;
        float l2 = asv[s * 4 + 2] + ad2_; l2 = l2 > 0.f ? l2 : 0.2f * l2;
        float l3 = asv[s * 4 + 3] + ad3; l3 = l3 > 0.f ? l3 : 0.2f * l3;
        float w0 = __expf(l0 - m0), w1 = __expf(l1 - m1);
        float w2 = __expf(l2 - m2), w3 = __expf(l3 - m3);
        d0 += w0; d1 += w1; d2 += w2; d3 += w3;
        const bf16* hrow = h2 + (long)s * 512 + c;
        a0 += w0 * tof(hrow[0]);
        a1 += w1 * tof(hrow[128]);
        a2 += w2 * tof(hrow[256]);
        a3 += w3 * tof(hrow[384]);
    }
    float v = a0 / (d0 + 1e-16f) + a1 / (d1 + 1e-16f) +
              a2 / (d2 + 1e-16f) + a3 / (d3 + 1e-16f);
    emb[(long)d * 128 + c] = 0.25f * v + b2[c];
}

// ---- final linear: out[N,64] = emb[N,128] @ W_lin + b -------------------
__global__ __launch_bounds__(256) void final_k(const float* __restrict__ emb,
                                               const float* __restrict__ W,
                                               const float* __restrict__ bias,
                                               float* __restrict__ out, int N)
{
    __shared__ float Ws[128 * 64];
    __shared__ float Es[4][132];
    const int tid = threadIdx.x;
    for (int i = tid; i < 128 * 64; i += 256) Ws[i] = W[i];
    int node0 = blockIdx.x * 4;
    for (int i = tid; i < 512; i += 256) {
        int nn = i >> 7, c = i & 127;
        int n = node0 + nn;
        Es[nn][c] = (n < N) ? emb[(long)n * 128 + c] : 0.f;
    }
    __syncthreads();
    int nn = tid >> 6, j = tid & 63;
    int n = node0 + nn;
    if (n >= N) return;
    float acc = bias[j];
#pragma unroll 8
    for (int k = 0; k < 128; ++k) acc += Es[nn][k] * Ws[k * 64 + j];
    out[(long)n * 64 + j] = acc;
}

// ---- diagnostic ---------------------------------------------------------
__global__ void diag_k(float* __restrict__ out, long n, float val)
{
    long i = (long)blockIdx.x * blockDim.x + threadIdx.x;
    if (i >= n) return;
    out[i] = val;
}

extern "C" void kernel_launch(void* const* d_in, const int* in_sizes, int n_in,
                              void* d_out, int out_size, void* d_ws, size_t ws_size,
                              hipStream_t stream)
{
    const float* x   = (const float*)d_in[0];
    const int* ei    = (const int*)d_in[1];
    const float* W1  = (const float*)d_in[2];
    const float* as1 = (const float*)d_in[3];
    const float* ad1 = (const float*)d_in[4];
    const float* b1  = (const float*)d_in[5];
    const float* W2  = (const float*)d_in[6];
    const float* as2 = (const float*)d_in[7];
    const float* ad2 = (const float*)d_in[8];
    const float* b2  = (const float*)d_in[9];
    const float* Wl  = (const float*)d_in[10];
    const float* bl  = (const float*)d_in[11];

    const int N = in_sizes[0] / 512;
    const int E = in_sizes[1] / 2;
    const int Etot = E + N;
    const int* src = ei;
    const int* dst = ei + E;

    float* outp = (float*)d_out;          // [N,64]
    float* embp = outp + (size_t)N * 64;  // [N,128] f32
    // out1b (bf16 [N,128]) parked inside the embp region (dead before agg2 writes emb)
    bf16* out1b = (bf16*)embp;

    // ---- workspace layout (~110 MB; known-safe floor from R3 diag = 119.6 MB) ----
    // h2 bf16 [N,512] at base; h1 bf16 [N,128] aliases its head (dead before gemm2).
    char* wsb = (char*)d_ws;
    bf16*  h2    = (bf16*)wsb;                              // N*512 bf16
    bf16*  h1    = (bf16*)wsb;                              // N*128 bf16 (alias)
    float* asv   = (float*)(wsb + (size_t)N * 512 * sizeof(bf16));  // N*4
    float* adv   = asv + (size_t)N * 4;                     // N*4
    int*   cnt   = (int*)(adv + (size_t)N * 4);             // N
    int*   row_ptr = cnt + N;                               // N+1
    int*   wofs  = row_ptr + (N + 1);                       // N
    int*   bsum  = wofs + N;                                // 512
    int*   bofs  = bsum + 512;                              // 512
    int*   eidx  = bofs + 512;                              // Etot
    size_t need  = (size_t)((char*)(eidx + Etot) - wsb);

    dim3 blk(256);
    long n_out_total = (long)N * 192;

    if (ws_size < need) {
        float val = 100.0f + (float)(ws_size >> 20);
        diag_k<<<(int)((n_out_total + 255) / 256), blk, 0, stream>>>(outp, n_out_total, val);
        return;
    }

    const int gMy = (N + 63) / 64;
    const int B = (N + 255) / 256;  // scan blocks (<=512 for N<=131072)

    // ---- CSR build (by dst) ----
    init_cnt_k<<<B, blk, 0, stream>>>(cnt, N);
    hist_k<<<(E + 255) / 256, blk, 0, stream>>>(dst, E, cnt);
    scan_blk_k<<<B, blk, 0, stream>>>(cnt, row_ptr, bsum, N);
    scan_top_k<<<1, 512, 0, stream>>>(bsum, bofs, B);
    add_off_k<<<B, blk, 0, stream>>>(row_ptr, bofs, wofs, N, Etot);
    scatter_k<<<(Etot + 255) / 256, blk, 0, stream>>>(dst, E, Etot, wofs, eidx);

    // ---- layer 1 ----
    gemm_tiled<float, float, bf16><<<dim3(2, gMy), blk, 0, stream>>>(x, W1, h1, N, 128, 512, 128);
    alpha4_k<<<(N * 4 + 255) / 256, blk, 0, stream>>>(h1, as1, ad1, asv, adv, N);
    agg1_gather_k<<<N, 128, 0, stream>>>(row_ptr, eidx, src, E, asv, adv, h1, b1, out1b);

    // ---- layer 2 (all heads fused) ----
    gemm_tiled<bf16, float, bf16><<<dim3(8, gMy), blk, 0, stream>>>(out1b, W2, h2, N, 512, 128, 512);
    alpha2w_k<<<N, 256, 0, stream>>>(h2, as2, ad2, asv, adv, N);
    agg2_gather_k<<<N, 128, 0, stream>>>(row_ptr, eidx, src, E, asv, adv, h2, b2, embp);

    // ---- head ----
    final_k<<<(N + 3) / 4, blk, 0, stream>>>(embp, Wl, bl, outp, N);
}